// Round 4
// baseline (3331.060 us; speedup 1.0000x reference)
//
#include <hip/hip_runtime.h>
#include <cstddef>

#define Bn 32
#define Sn 2048
#define Hn 256
#define Ln 2

typedef float f32x2 __attribute__((ext_vector_type(2)));

__device__ __forceinline__ float tanh_fast(float x) {
  // tanh(x) = 1 - 2/(exp(2x)+1); saturates correctly at +/-inf
  float e = __expf(2.0f * x);
  return 1.0f - 2.0f / (e + 1.0f);
}

// ---------------------------------------------------------------------------
// Projection GEMM: C[M,N] = A[M,K] * W[N,K]^T + bias[N]   (unchanged)
// ---------------------------------------------------------------------------
__global__ __launch_bounds__(256) void proj_gemm(
    const float* __restrict__ A,
    const float* __restrict__ W,
    const float* __restrict__ bias,
    float* __restrict__ C)
{
  __shared__ float As[64][68];
  __shared__ float Bs[64][68];
  const int tid = threadIdx.x;
  const int tx = tid & 15;   // N direction
  const int ty = tid >> 4;   // M direction
  const size_t m0 = (size_t)blockIdx.y * 64;
  const int n0 = blockIdx.x * 64;

  float acc[4][4];
#pragma unroll
  for (int i = 0; i < 4; ++i)
#pragma unroll
    for (int j = 0; j < 4; ++j) acc[i][j] = 0.0f;

  for (int kc = 0; kc < Hn; kc += 64) {
#pragma unroll
    for (int r = 0; r < 4; ++r) {
      int idx = tid + 256 * r;
      int mm = idx >> 4;
      int kk = (idx & 15) << 2;
      float4 av = *(const float4*)&A[(m0 + (size_t)mm) * Hn + kc + kk];
      As[kk + 0][mm] = av.x; As[kk + 1][mm] = av.y;
      As[kk + 2][mm] = av.z; As[kk + 3][mm] = av.w;
      float4 wv = *(const float4*)&W[(size_t)(n0 + mm) * Hn + kc + kk];
      Bs[kk + 0][mm] = wv.x; Bs[kk + 1][mm] = wv.y;
      Bs[kk + 2][mm] = wv.z; Bs[kk + 3][mm] = wv.w;
    }
    __syncthreads();
#pragma unroll
    for (int k = 0; k < 64; ++k) {
      float4 a = *(const float4*)&As[k][ty << 2];
      float4 b = *(const float4*)&Bs[k][tx << 2];
      float av4[4] = {a.x, a.y, a.z, a.w};
      float bv4[4] = {b.x, b.y, b.z, b.w};
#pragma unroll
      for (int i = 0; i < 4; ++i)
#pragma unroll
        for (int j = 0; j < 4; ++j)
          acc[i][j] += av4[i] * bv4[j];
    }
    __syncthreads();
  }

  float4 bv = *(const float4*)&bias[n0 + (tx << 2)];
  float badd[4] = {bv.x, bv.y, bv.z, bv.w};
#pragma unroll
  for (int i = 0; i < 4; ++i) {
    float4 o;
    o.x = acc[i][0] + badd[0];
    o.y = acc[i][1] + badd[1];
    o.z = acc[i][2] + badd[2];
    o.w = acc[i][3] + badd[3];
    *(float4*)&C[(m0 + (size_t)((ty << 2) + i)) * Hn + n0 + (tx << 2)] = o;
  }
}

// ---------------------------------------------------------------------------
// Recurrence: one workgroup per batch, 512 threads (8 waves).
// Wave w owns k-chunk [32w,32w+32) AND outputs [32w,32w+32).
//   - __launch_bounds__(512, 2): 2 waves/SIMD -> 256 ArchVGPR budget so
//     Wreg (128 regs) stays OUT of AGPRs (round 3: VGPR_Count=92 proved the
//     compiler parked W in AGPRs -> v_accvgpr_read tax on every FMA).
//   - h broadcast via v_readlane -> 16 SGPR PAIRS consumed directly by
//     v_pk_fma_f32 (VOP3P allows one SGPR-pair src). Eliminates the hbuf
//     LDS round-trip (write + wave_barrier + 16 ds_reads ~200 cyc) from the
//     per-step critical path; wave w's next h chunk is exactly what its own
//     lanes 0..31 just computed, so NO second barrier of any kind.
//   - partials slot-major, row stride 10, slot XOR-swizzled by (lane>>3)&3:
//       write bank (10l + w^((l>>3)&3)) % 32: l/l+16 now differ (+-2), only
//       l/l+32 alias -> 2-way = free. Reads: 8B-aligned ds_read_b64, upper
//       half-wave same-addr broadcast, l/l+16 2-way = free. Swizzle is a
//       per-row slot permutation; reduce sums all 8 slots -> invariant.
//   - single raw s_barrier per step (lgkmcnt-only wait: y-stores and xp
//     prefetch stay in flight), partials double-buffered (s&1) so the
//     pre-barrier lgkmcnt(0) makes one barrier/step WAR-safe.
// ---------------------------------------------------------------------------
#define PSTR 10
#define PBUF (Hn * PSTR)   // 2560 words per buffer

__global__ __launch_bounds__(512, 2) void rnn_rec(
    const float* __restrict__ xp,   // [Bn,Sn,Hn] precomputed input projection
    const float* __restrict__ Whh,  // [Hn,Hn]
    const float* __restrict__ bhh,  // [Hn]
    const float* __restrict__ h0,   // [Bn,Hn] (layer slice)
    float* __restrict__ y,          // [Bn,Sn,Hn] layer outputs
    float* __restrict__ hfin)       // [Bn,Hn] final hidden (layer slice)
{
  const int b = blockIdx.x;
  const int t = threadIdx.x;
  const int lane = t & 63;
  const int w = t >> 6;                   // 0..7
  const int ocol = 32 * w + (lane & 31);  // output this lane reduces

  __shared__ float part[2 * PBUF];  // 2 x 10240 B

  // Wreg[r][c2] = (Whh[lane+64r][32w+2c2], Whh[lane+64r][32w+2c2+1])
  f32x2 Wreg[4][16];
#pragma unroll
  for (int r = 0; r < 4; ++r)
#pragma unroll
    for (int q = 0; q < 8; ++q) {
      float4 v = *(const float4*)&Whh[(size_t)(lane + 64 * r) * Hn + 32 * w + 4 * q];
      Wreg[r][2 * q + 0] = f32x2{v.x, v.y};
      Wreg[r][2 * q + 1] = f32x2{v.z, v.w};
    }

  // partial-write base: row = lane (+64r), slot = w ^ ((lane>>3)&3)
  const int pw0 = PSTR * lane + (w ^ ((lane >> 3) & 3));

  const float* xp_b = xp + (size_t)b * Sn * Hn;
  float* y_b = y + (size_t)b * Sn * Hn;
  const float bias = bhh[ocol];

  // per-lane hidden value for output ocol (lanes l and l+32 duplicate)
  float hn = h0[(size_t)b * Hn + ocol];
  float xp_cur = xp_b[ocol];

  // broadcast h -> 16 wave-uniform SGPR pairs
  f32x2 hs[16];
#pragma unroll
  for (int c = 0; c < 16; ++c) {
    int hni = __float_as_int(hn);
    float lo = __int_as_float(__builtin_amdgcn_readlane(hni, 2 * c));
    float hi = __int_as_float(__builtin_amdgcn_readlane(hni, 2 * c + 1));
    hs[c] = f32x2{lo, hi};
  }

  for (int s = 0; s < Sn; ++s) {
    // prefetch next step's xp; consumed after the barrier -> latency hidden
    float xp_next = (s + 1 < Sn) ? xp_b[(size_t)(s + 1) * Hn + ocol] : 0.0f;

    // ---- FMA phase: 64 v_pk_fma_f32/lane, W in ArchVGPRs, h in SGPR pairs
    f32x2 acc0 = {0.f, 0.f}, acc1 = {0.f, 0.f}, acc2 = {0.f, 0.f}, acc3 = {0.f, 0.f};
#pragma unroll
    for (int c = 0; c < 16; ++c) {
      asm("v_pk_fma_f32 %0, %1, %2, %0" : "+v"(acc0) : "v"(Wreg[0][c]), "s"(hs[c]));
      asm("v_pk_fma_f32 %0, %1, %2, %0" : "+v"(acc1) : "v"(Wreg[1][c]), "s"(hs[c]));
      asm("v_pk_fma_f32 %0, %1, %2, %0" : "+v"(acc2) : "v"(Wreg[2][c]), "s"(hs[c]));
      asm("v_pk_fma_f32 %0, %1, %2, %0" : "+v"(acc3) : "v"(Wreg[3][c]), "s"(hs[c]));
    }
    float* pbuf = &part[(s & 1) * PBUF];
    pbuf[pw0       ] = acc0.x + acc0.y;
    pbuf[pw0 +  640] = acc1.x + acc1.y;
    pbuf[pw0 + 1280] = acc2.x + acc2.y;
    pbuf[pw0 + 1920] = acc3.x + acc3.y;

    // partials visible to all waves; no vmcnt drain (y/xp stay in flight)
    asm volatile("s_waitcnt lgkmcnt(0)" ::: "memory");
    __builtin_amdgcn_s_barrier();
    __builtin_amdgcn_sched_barrier(0);

    // ---- reduce: every lane sums all 8 slots of its output (no shuffle)
    const f32x2* prow = (const f32x2*)&pbuf[PSTR * ocol];
    f32x2 p0 = prow[0], p1 = prow[1], p2 = prow[2], p3 = prow[3];
    f32x2 q01 = p0 + p1;          // v_pk_add_f32
    f32x2 q23 = p2 + p3;
    f32x2 qq = q01 + q23;
    hn = tanh_fast((qq.x + qq.y) + xp_cur + bias);

    // broadcast new h for next step (replaces the old hbuf round-trip)
#pragma unroll
    for (int c = 0; c < 16; ++c) {
      int hni = __float_as_int(hn);
      float lo = __int_as_float(__builtin_amdgcn_readlane(hni, 2 * c));
      float hi = __int_as_float(__builtin_amdgcn_readlane(hni, 2 * c + 1));
      hs[c] = f32x2{lo, hi};
    }

    if (lane < 32) y_b[(size_t)s * Hn + ocol] = hn;   // fire-and-forget
    xp_cur = xp_next;
  }

  if (lane < 32) hfin[(size_t)b * Hn + ocol] = hn;
}

// ---------------------------------------------------------------------------
// Phases (stream-ordered):
//  1. proj1: xp1 = x * Wih0^T + bih0          -> ws
//  2. rec1 : layer-1 recurrence, y1 -> d_out, fin0 -> d_out tail
//  3. proj2: xp2 = y1 * Wih1^T + bih1         -> ws (reuse)
//  4. rec2 : layer-2 recurrence, y2 -> d_out (final), fin1 -> d_out tail
// ws needs Bn*Sn*Hn*4 = 64 MiB.
// ---------------------------------------------------------------------------
extern "C" void kernel_launch(void* const* d_in, const int* in_sizes, int n_in,
                              void* d_out, int out_size, void* d_ws, size_t ws_size,
                              hipStream_t stream) {
  const float* x   = (const float*)d_in[0];
  const float* h0  = (const float*)d_in[1];
  const float* Wih = (const float*)d_in[2];
  const float* Whh = (const float*)d_in[3];
  const float* bih = (const float*)d_in[4];
  const float* bhh = (const float*)d_in[5];

  float* out = (float*)d_out;
  float* yout = out;                              // [Bn,Sn,Hn]
  float* fin  = out + (size_t)Bn * Sn * Hn;       // [Ln,Bn,Hn]
  float* xpws = (float*)d_ws;                     // [Bn,Sn,Hn] scratch

  dim3 pgrid(Hn / 64, (Bn * Sn) / 64);

  // layer 1
  proj_gemm<<<pgrid, 256, 0, stream>>>(x, Wih, bih, xpws);
  rnn_rec<<<Bn, 512, 0, stream>>>(xpws, Whh, bhh, h0, yout, fin);

  // layer 2 (input = y1 currently residing in d_out)
  proj_gemm<<<pgrid, 256, 0, stream>>>(yout, Wih + Hn * Hn, bih + Hn, xpws);
  rnn_rec<<<Bn, 512, 0, stream>>>(xpws, Whh + Hn * Hn, bhh + Hn,
                                  h0 + Bn * Hn, yout, fin + Bn * Hn);
}

// Round 5
// 2309.374 us; speedup vs baseline: 1.4424x; 1.4424x over previous
//
#include <hip/hip_runtime.h>
#include <cstddef>

#define Bn 32
#define Sn 2048
#define Hn 256
#define Ln 2
#define CHUNK 64
#define NCHUNK (Sn / CHUNK)   // 32

#define PSTRIDE 9
#define PBUF (Hn * PSTRIDE)   // 2304 words per partial buffer

// ---------------------------------------------------------------------------
// Pipeline flags (chunk-granular, monotone counters). Zeroed by zero_flags_k
// at the head of the stream each launch (graph-replay safe).
//   [0*Bn..1*Bn): xp1 ready, N-half 0     (proj1 worker j=0 publishes)
//   [1*Bn..2*Bn): xp1 ready, N-half 1
//   [2*Bn..3*Bn): y1 chunks done          (rec1 publishes)
//   [3*Bn..4*Bn): xp2 ready, N-half 0     (proj2 worker j=0 publishes)
//   [4*Bn..5*Bn): xp2 ready, N-half 1
// ---------------------------------------------------------------------------
__device__ unsigned g_flags[5 * Bn];

__global__ void zero_flags_k() {
  int i = threadIdx.x;
  if (i < 5 * Bn) g_flags[i] = 0;
}

__device__ __forceinline__ float tanh_fast(float x) {
  // tanh(x) = 1 - 2/(exp(2x)+1); saturates correctly at +/-inf
  float e = __expf(2.0f * x);
  return 1.0f - 2.0f / (e + 1.0f);
}

__device__ __forceinline__ void wait_ge(unsigned* f, unsigned tgt) {
  while (__hip_atomic_load(f, __ATOMIC_ACQUIRE, __HIP_MEMORY_SCOPE_AGENT) < tgt)
    __builtin_amdgcn_s_sleep(8);
}

// ---------------------------------------------------------------------------
// Recurrence body — EXACT round-2 structure (measured 1235 us/layer, 0 LDS
// conflicts), wrapped in a chunk loop with flag wait/publish.
//   wave w owns k-chunk [32w,32w+32) and outputs [32w,32w+32)
//   partials at part[9*o + w]: write bank (9l+w)%32 -> 2-way only (free)
//   single raw s_barrier per step, partials double-buffered on (s&1)
//   reduce: lane sums 4 of 8 slots + one shfl_xor(32)
//   h exchange via hbuf LDS (wave-local readback, wave_barrier only)
// Chunk edits: acquire xp chunk flags at chunk start (t0 spin + barrier) and
// reload xp_cur fresh (the cross-chunk prefetch may predate the flag);
// publish y-progress (rec1 only): vmcnt drain + barrier + t0 release store.
// ---------------------------------------------------------------------------
__device__ void rec_body(const float* __restrict__ xp_b,
                         const float* __restrict__ Whh,
                         const float* __restrict__ bhh,
                         const float* __restrict__ h0_b,
                         float* __restrict__ y_b,
                         float* __restrict__ hfin_b,
                         unsigned* waitA, unsigned* waitB, unsigned* pub,
                         float* part, float* hbuf) {
  const int t = threadIdx.x;
  const int lane = t & 63;
  const int w = t >> 6;                   // 0..7
  const int ocol = 32 * w + (lane & 31);  // output this lane reduces
  const int hh = lane >> 5;               // which half of the 8 slots

  // Wreg[r][c] = Whh[lane + 64r][32w + c]
  float Wreg[4][32];
#pragma unroll
  for (int r = 0; r < 4; ++r)
#pragma unroll
    for (int q = 0; q < 8; ++q) {
      float4 v = *(const float4*)&Whh[(size_t)(lane + 64 * r) * Hn + 32 * w + 4 * q];
      Wreg[r][4 * q + 0] = v.x; Wreg[r][4 * q + 1] = v.y;
      Wreg[r][4 * q + 2] = v.z; Wreg[r][4 * q + 3] = v.w;
    }

  const int pw0 = PSTRIDE * lane + w;
  const float bias = bhh[ocol];

  float hv[32];
#pragma unroll
  for (int j = 0; j < 8; ++j)
    *(float4*)&hv[4 * j] = *(const float4*)&h0_b[32 * w + 4 * j];

  float xp_cur = 0.0f;

  for (int c = 0; c < NCHUNK; ++c) {
    // acquire this chunk's xp (both N-halves)
    if (t == 0) { wait_ge(waitA, c + 1); wait_ge(waitB, c + 1); }
    __syncthreads();
    // fresh load: the prefetched value crossed the chunk boundary pre-flag
    xp_cur = xp_b[(size_t)(c * CHUNK) * Hn + ocol];

    for (int ss = 0; ss < CHUNK; ++ss) {
      const int s = c * CHUNK + ss;
      float xp_next = (s + 1 < Sn) ? xp_b[(size_t)(s + 1) * Hn + ocol] : 0.0f;

      float a0 = 0.f, a1 = 0.f, a2 = 0.f, a3 = 0.f;
#pragma unroll
      for (int cc = 0; cc < 32; ++cc) {
        a0 += Wreg[0][cc] * hv[cc];
        a1 += Wreg[1][cc] * hv[cc];
        a2 += Wreg[2][cc] * hv[cc];
        a3 += Wreg[3][cc] * hv[cc];
      }
      float* pbuf = &part[(s & 1) * PBUF];
      pbuf[pw0       ] = a0;
      pbuf[pw0 +  576] = a1;
      pbuf[pw0 + 1152] = a2;
      pbuf[pw0 + 1728] = a3;

      asm volatile("s_waitcnt lgkmcnt(0)" ::: "memory");
      __builtin_amdgcn_s_barrier();
      __builtin_amdgcn_sched_barrier(0);

      const float* prow = &pbuf[PSTRIDE * ocol + 4 * hh];
      float r0 = prow[0], r1 = prow[1], r2 = prow[2], r3 = prow[3];
      float s4 = (r0 + r1) + (r2 + r3);
      float tot = s4 + __shfl_xor(s4, 32, 64);
      float hn = tanh_fast(tot + xp_cur + bias);
      if (lane < 32) {
        hbuf[ocol] = hn;
        y_b[(size_t)s * Hn + ocol] = hn;   // fire-and-forget global store
      }
      xp_cur = xp_next;

      __builtin_amdgcn_wave_barrier();     // keep reads after the write
#pragma unroll
      for (int j = 0; j < 8; ++j)
        *(float4*)&hv[4 * j] = *(const float4*)&hbuf[32 * w + 4 * j];
    }

    if (pub) {
      // y stores of this chunk must be globally visible before the flag
      asm volatile("s_waitcnt vmcnt(0)" ::: "memory");
      __syncthreads();
      if (t == 0)
        __hip_atomic_store(pub, (unsigned)(c + 1), __ATOMIC_RELEASE,
                           __HIP_MEMORY_SCOPE_AGENT);
    }
  }

  if (lane < 32) hfin_b[ocol] = hbuf[ocol];
}

// ---------------------------------------------------------------------------
// Projection worker: per (batch, N-half). For each chunk c: GEMM
//   C[64, 128-half] = A[64,256] * W[half,256]^T + bias
// 512 threads, 64x64 tiles (2 per chunk), K staged in 64-chunks (same
// layout/order as the original proj_gemm -> identical summation order).
// ---------------------------------------------------------------------------
__device__ void proj_body(const float* __restrict__ Ab,
                          const float* __restrict__ W,
                          const float* __restrict__ bias,
                          float* __restrict__ Cb,
                          unsigned* waitf, unsigned* pub, int jhalf,
                          float* smem) {
  const int t = threadIdx.x;
  const int tx = t & 15;    // 4 cols each
  const int ty = t >> 4;    // 0..31, 2 rows each
  float (*As)[68] = (float(*)[68])smem;
  float (*Bs)[68] = (float(*)[68])(smem + 64 * 68);

  for (int c = 0; c < NCHUNK; ++c) {
    if (waitf) {
      if (t == 0) wait_ge(waitf, c + 1);
      __syncthreads();
    }
    const float* A = Ab + (size_t)(c * CHUNK) * Hn;
    float* C = Cb + (size_t)(c * CHUNK) * Hn;

    for (int nt = 2 * jhalf; nt < 2 * jhalf + 2; ++nt) {
      const int n0 = nt * 64;
      float acc[2][4] = {{0.f, 0.f, 0.f, 0.f}, {0.f, 0.f, 0.f, 0.f}};
      for (int kc = 0; kc < Hn; kc += 64) {
#pragma unroll
        for (int r = 0; r < 2; ++r) {
          int idx = t + 512 * r;           // 0..1023 -> 64 rows x 16 float4
          int mm = idx >> 4;
          int kk = (idx & 15) << 2;
          float4 av = *(const float4*)&A[(size_t)mm * Hn + kc + kk];
          As[kk + 0][mm] = av.x; As[kk + 1][mm] = av.y;
          As[kk + 2][mm] = av.z; As[kk + 3][mm] = av.w;
          float4 wv = *(const float4*)&W[(size_t)(n0 + mm) * Hn + kc + kk];
          Bs[kk + 0][mm] = wv.x; Bs[kk + 1][mm] = wv.y;
          Bs[kk + 2][mm] = wv.z; Bs[kk + 3][mm] = wv.w;
        }
        __syncthreads();
#pragma unroll
        for (int k = 0; k < 64; ++k) {
          float a0 = As[k][2 * ty], a1 = As[k][2 * ty + 1];
          float4 bv = *(const float4*)&Bs[k][tx << 2];
          acc[0][0] += a0 * bv.x; acc[0][1] += a0 * bv.y;
          acc[0][2] += a0 * bv.z; acc[0][3] += a0 * bv.w;
          acc[1][0] += a1 * bv.x; acc[1][1] += a1 * bv.y;
          acc[1][2] += a1 * bv.z; acc[1][3] += a1 * bv.w;
        }
        __syncthreads();
      }
      float4 bb = *(const float4*)&bias[n0 + (tx << 2)];
#pragma unroll
      for (int i = 0; i < 2; ++i) {
        float4 o;
        o.x = acc[i][0] + bb.x; o.y = acc[i][1] + bb.y;
        o.z = acc[i][2] + bb.z; o.w = acc[i][3] + bb.w;
        *(float4*)&C[(size_t)(2 * ty + i) * Hn + n0 + (tx << 2)] = o;
      }
    }

    if (pub) {
      asm volatile("s_waitcnt vmcnt(0)" ::: "memory");
      __syncthreads();
      if (t == 0)
        __hip_atomic_store(pub, (unsigned)(c + 1), __ATOMIC_RELEASE,
                           __HIP_MEMORY_SCOPE_AGENT);
    }
  }
}

// ---------------------------------------------------------------------------
// Fused pipeline kernel. 192 blocks x 512 threads:
//   [  0, 32): rec1, batch b            waits xp1[b], publishes y1[b]
//   [ 32, 64): rec2, batch b            waits xp2[b]
//   [ 64,128): proj1 worker (b, jhalf)  publishes xp1 half
//   [128,192): proj2 worker (b, jhalf)  waits y1[b], publishes xp2 half
// xp2 overwrites xp1 in place in ws (rec1 is past chunk c before proj2
// writes it -- ordered through the y1 flag), so ws stays 64 MiB.
// rec2 writes y2 over y1 only for chunks proj2 has already consumed.
// ---------------------------------------------------------------------------
__global__ __launch_bounds__(512) void fused(
    const float* __restrict__ x, const float* __restrict__ h0,
    const float* __restrict__ Wih, const float* __restrict__ Whh,
    const float* __restrict__ bih, const float* __restrict__ bhh,
    float* __restrict__ yout, float* __restrict__ fin,
    float* __restrict__ xpws) {
  __shared__ float smem[2 * 64 * 68];   // 34.8 KB; rec carves part+hbuf from it
  const int bid = blockIdx.x;

  if (bid < 32) {
    const int b = bid;
    rec_body(xpws + (size_t)b * Sn * Hn, Whh, bhh, h0 + (size_t)b * Hn,
             yout + (size_t)b * Sn * Hn, fin + (size_t)b * Hn,
             &g_flags[0 * Bn + b], &g_flags[1 * Bn + b], &g_flags[2 * Bn + b],
             smem, smem + 2 * PBUF);
  } else if (bid < 64) {
    const int b = bid - 32;
    rec_body(xpws + (size_t)b * Sn * Hn, Whh + Hn * Hn, bhh + Hn,
             h0 + (size_t)Bn * Hn + (size_t)b * Hn,
             yout + (size_t)b * Sn * Hn, fin + (size_t)Bn * Hn + (size_t)b * Hn,
             &g_flags[3 * Bn + b], &g_flags[4 * Bn + b], nullptr,
             smem, smem + 2 * PBUF);
  } else if (bid < 128) {
    const int q = bid - 64;
    const int b = q & 31, j = q >> 5;
    proj_body(x + (size_t)b * Sn * Hn, Wih, bih, xpws + (size_t)b * Sn * Hn,
              nullptr, &g_flags[j * Bn + b], j, smem);
  } else {
    const int q = bid - 128;
    const int b = q & 31, j = q >> 5;
    proj_body(yout + (size_t)b * Sn * Hn, Wih + Hn * Hn, bih + Hn,
              xpws + (size_t)b * Sn * Hn,
              &g_flags[2 * Bn + b], &g_flags[(3 + j) * Bn + b], j, smem);
  }
}

// ---------------------------------------------------------------------------
// Launch: zero flags, then the single fused pipeline kernel.
// ws needs Bn*Sn*Hn*4 = 64 MiB (xp buffer, shared by both layers in-place).
// ---------------------------------------------------------------------------
extern "C" void kernel_launch(void* const* d_in, const int* in_sizes, int n_in,
                              void* d_out, int out_size, void* d_ws, size_t ws_size,
                              hipStream_t stream) {
  const float* x   = (const float*)d_in[0];
  const float* h0  = (const float*)d_in[1];
  const float* Wih = (const float*)d_in[2];
  const float* Whh = (const float*)d_in[3];
  const float* bih = (const float*)d_in[4];
  const float* bhh = (const float*)d_in[5];

  float* out = (float*)d_out;
  float* yout = out;                              // [Bn,Sn,Hn]
  float* fin  = out + (size_t)Bn * Sn * Hn;       // [Ln,Bn,Hn]
  float* xpws = (float*)d_ws;                     // [Bn,Sn,Hn] scratch

  zero_flags_k<<<1, 192, 0, stream>>>();
  fused<<<192, 512, 0, stream>>>(x, h0, Wih, Whh, bih, bhh, yout, fin, xpws);
}

// Round 6
// 2034.108 us; speedup vs baseline: 1.6376x; 1.1353x over previous
//
#include <hip/hip_runtime.h>
#include <cstddef>

#define Bn 32
#define Sn 2048
#define Hn 256
#define Ln 2
#define CHUNK 64
#define NCHUNK (Sn / CHUNK)   // 32

#define PSTRIDE 9
#define PBUF (Hn * PSTRIDE)   // 2304 words per partial buffer

// ---------------------------------------------------------------------------
// Pipeline flags (chunk-granular monotone counters), zeroed each launch by
// zero_flags_k (stream-ordered, graph-replay safe).
//   [0*Bn..1*Bn): xp1[b] chunks ready   (proj1 publishes)
//   [1*Bn..2*Bn): y1[b] chunks done     (rec1 publishes)
//   [2*Bn..3*Bn): xp2[b] chunks ready   (proj2 publishes)
// ---------------------------------------------------------------------------
__device__ unsigned g_flags[3 * Bn];

__global__ void zero_flags_k() {
  int i = threadIdx.x;
  if (i < 3 * Bn) g_flags[i] = 0;
}

__device__ __forceinline__ float tanh_fast(float x) {
  // tanh(x) = 1 - 2/(exp(2x)+1); saturates correctly at +/-inf
  float e = __expf(2.0f * x);
  return 1.0f - 2.0f / (e + 1.0f);
}

// RELAXED poll (no per-iteration L2 invalidate!), single acquire-side fence
// after the flag trips. Round 5's ACQUIRE-per-poll invalidated the polling
// XCD's L2 every ~0.25us from ~96 pollers -> poisoned every xp prefetch.
__device__ __forceinline__ void wait_ge(unsigned* f, unsigned tgt) {
  while (__hip_atomic_load(f, __ATOMIC_RELAXED, __HIP_MEMORY_SCOPE_AGENT) < tgt)
    __builtin_amdgcn_s_sleep(2);
  __threadfence();   // one inv/wb per handoff, not per poll
}

// publisher: all threads drain their stores, then t0 fences + stores flag
__device__ __forceinline__ void publish(unsigned* f, unsigned val, int t) {
  asm volatile("s_waitcnt vmcnt(0)" ::: "memory");
  __syncthreads();
  if (t == 0) {
    __threadfence();
    __hip_atomic_store(f, val, __ATOMIC_RELAXED, __HIP_MEMORY_SCOPE_AGENT);
  }
}

// ---------------------------------------------------------------------------
// Recurrence body — EXACT round-2 step structure (measured 603 ns/step, 0
// LDS conflicts), chunked with flag wait/publish and DEPTH-2 xp prefetch.
//   wave w owns k-chunk [32w,32w+32) and outputs [32w,32w+32)
//   partials at part[9*o + w]: write bank (9l+w)%32 -> 2-way only (free)
//   single raw s_barrier per step, partials double-buffered on (s&1)
//   reduce: lane sums 4 of 8 slots + one shfl_xor(32)
//   h exchange via hbuf LDS (wave-local readback, wave_barrier only)
// Chunk boundary: t0 relaxed-spin + fence, syncthreads, first TWO xp
// elements loaded fresh (they are exactly the slots the cross-chunk
// prefetch may have filled with stale data).
// ---------------------------------------------------------------------------
__device__ void rec_body(const float* __restrict__ xp_b,
                         const float* __restrict__ Whh,
                         const float* __restrict__ bhh,
                         const float* __restrict__ h0_b,
                         float* __restrict__ y_b,
                         float* __restrict__ hfin_b,
                         unsigned* waitf, unsigned* pub,
                         float* part, float* hbuf) {
  const int t = threadIdx.x;
  const int lane = t & 63;
  const int w = t >> 6;                   // 0..7
  const int ocol = 32 * w + (lane & 31);  // output this lane reduces
  const int hh = lane >> 5;               // which half of the 8 slots

  // Wreg[r][c] = Whh[lane + 64r][32w + c]
  float Wreg[4][32];
#pragma unroll
  for (int r = 0; r < 4; ++r)
#pragma unroll
    for (int q = 0; q < 8; ++q) {
      float4 v = *(const float4*)&Whh[(size_t)(lane + 64 * r) * Hn + 32 * w + 4 * q];
      Wreg[r][4 * q + 0] = v.x; Wreg[r][4 * q + 1] = v.y;
      Wreg[r][4 * q + 2] = v.z; Wreg[r][4 * q + 3] = v.w;
    }

  const int pw0 = PSTRIDE * lane + w;
  const float bias = bhh[ocol];

  float hv[32];
#pragma unroll
  for (int j = 0; j < 8; ++j)
    *(float4*)&hv[4 * j] = *(const float4*)&h0_b[32 * w + 4 * j];

  for (int c = 0; c < NCHUNK; ++c) {
    // acquire this chunk's xp
    if (t == 0) wait_ge(waitf, c + 1);
    __syncthreads();

    const int s0 = c * CHUNK;
    // fresh loads of the two slots the cross-chunk prefetch may have staled
    float xp_cur = xp_b[(size_t)s0 * Hn + ocol];
    float xp_n1  = xp_b[(size_t)(s0 + 1) * Hn + ocol];

    for (int ss = 0; ss < CHUNK; ++ss) {
      const int s = s0 + ss;
      // depth-2 prefetch: consumed two steps later (~1.2us of cover)
      float xp_n2 = (s + 2 < Sn) ? xp_b[(size_t)(s + 2) * Hn + ocol] : 0.0f;

      float a0 = 0.f, a1 = 0.f, a2 = 0.f, a3 = 0.f;
#pragma unroll
      for (int cc = 0; cc < 32; ++cc) {
        a0 += Wreg[0][cc] * hv[cc];
        a1 += Wreg[1][cc] * hv[cc];
        a2 += Wreg[2][cc] * hv[cc];
        a3 += Wreg[3][cc] * hv[cc];
      }
      float* pbuf = &part[(s & 1) * PBUF];
      pbuf[pw0       ] = a0;
      pbuf[pw0 +  576] = a1;
      pbuf[pw0 + 1152] = a2;
      pbuf[pw0 + 1728] = a3;

      asm volatile("s_waitcnt lgkmcnt(0)" ::: "memory");
      __builtin_amdgcn_s_barrier();
      __builtin_amdgcn_sched_barrier(0);

      const float* prow = &pbuf[PSTRIDE * ocol + 4 * hh];
      float r0 = prow[0], r1 = prow[1], r2 = prow[2], r3 = prow[3];
      float s4 = (r0 + r1) + (r2 + r3);
      float tot = s4 + __shfl_xor(s4, 32, 64);
      float hn = tanh_fast(tot + xp_cur + bias);
      if (lane < 32) {
        hbuf[ocol] = hn;
        y_b[(size_t)s * Hn + ocol] = hn;   // fire-and-forget global store
      }
      xp_cur = xp_n1;
      xp_n1 = xp_n2;

      __builtin_amdgcn_wave_barrier();     // keep reads after the write
#pragma unroll
      for (int j = 0; j < 8; ++j)
        *(float4*)&hv[4 * j] = *(const float4*)&hbuf[32 * w + 4 * j];
    }

    if (pub) publish(pub, (unsigned)(c + 1), t);
  }

  if (lane < 32) hfin_b[ocol] = hbuf[ocol];
}

// ---------------------------------------------------------------------------
// Projection worker: one block per (layer, batch). Per chunk c: full-width
//   C[64,256] = A[64,256] * W[256,256]^T + bias   as 4 64x64 N-tiles.
// 512 threads; K staged in 64-chunks, k ascending -> summation order
// identical to all prior rounds (absmax-stable). ~14us/chunk << 38.6us
// rec cadence, so proj never gates steady state.
// ---------------------------------------------------------------------------
__device__ void proj_body(const float* __restrict__ Ab,
                          const float* __restrict__ W,
                          const float* __restrict__ bias,
                          float* __restrict__ Cb,
                          unsigned* waitf, unsigned* pub,
                          float* smem) {
  const int t = threadIdx.x;
  const int tx = t & 15;    // 4 cols each
  const int ty = t >> 4;    // 0..31, 2 rows each
  float (*As)[68] = (float(*)[68])smem;
  float (*Bs)[68] = (float(*)[68])(smem + 64 * 68);

  for (int c = 0; c < NCHUNK; ++c) {
    if (waitf) {
      if (t == 0) wait_ge(waitf, c + 1);
      __syncthreads();
    }
    const float* A = Ab + (size_t)(c * CHUNK) * Hn;
    float* C = Cb + (size_t)(c * CHUNK) * Hn;

    for (int nt = 0; nt < 4; ++nt) {
      const int n0 = nt * 64;
      float acc[2][4] = {{0.f, 0.f, 0.f, 0.f}, {0.f, 0.f, 0.f, 0.f}};
      for (int kc = 0; kc < Hn; kc += 64) {
#pragma unroll
        for (int r = 0; r < 2; ++r) {
          int idx = t + 512 * r;           // 0..1023 -> 64 rows x 16 float4
          int mm = idx >> 4;
          int kk = (idx & 15) << 2;
          float4 av = *(const float4*)&A[(size_t)mm * Hn + kc + kk];
          As[kk + 0][mm] = av.x; As[kk + 1][mm] = av.y;
          As[kk + 2][mm] = av.z; As[kk + 3][mm] = av.w;
          float4 wv = *(const float4*)&W[(size_t)(n0 + mm) * Hn + kc + kk];
          Bs[kk + 0][mm] = wv.x; Bs[kk + 1][mm] = wv.y;
          Bs[kk + 2][mm] = wv.z; Bs[kk + 3][mm] = wv.w;
        }
        __syncthreads();
#pragma unroll
        for (int k = 0; k < 64; ++k) {
          float a0 = As[k][2 * ty], a1 = As[k][2 * ty + 1];
          float4 bv = *(const float4*)&Bs[k][tx << 2];
          acc[0][0] += a0 * bv.x; acc[0][1] += a0 * bv.y;
          acc[0][2] += a0 * bv.z; acc[0][3] += a0 * bv.w;
          acc[1][0] += a1 * bv.x; acc[1][1] += a1 * bv.y;
          acc[1][2] += a1 * bv.z; acc[1][3] += a1 * bv.w;
        }
        __syncthreads();
      }
      float4 bb = *(const float4*)&bias[n0 + (tx << 2)];
#pragma unroll
      for (int i = 0; i < 2; ++i) {
        float4 o;
        o.x = acc[i][0] + bb.x; o.y = acc[i][1] + bb.y;
        o.z = acc[i][2] + bb.z; o.w = acc[i][3] + bb.w;
        *(float4*)&C[(size_t)(2 * ty + i) * Hn + n0 + (tx << 2)] = o;
      }
    }

    if (pub) publish(pub, (unsigned)(c + 1), t);
  }
}

// ---------------------------------------------------------------------------
// Fused pipeline kernel. 128 blocks x 512 threads:
//   [  0, 32): rec1, batch b    waits xp1[b], publishes y1[b]
//   [ 32, 64): rec2, batch b    waits xp2[b]
//   [ 64, 96): proj1, batch b   publishes xp1[b]
//   [ 96,128): proj2, batch b   waits y1[b], publishes xp2[b]
// xp2 overwrites xp1 in place in ws (proj2 writes chunk c only after rec1
// published chunk c; rec1's prefetches into c+1 drained at that publish's
// vmcnt(0)), so ws stays 64 MiB.
// ---------------------------------------------------------------------------
__global__ __launch_bounds__(512) void fused(
    const float* __restrict__ x, const float* __restrict__ h0,
    const float* __restrict__ Wih, const float* __restrict__ Whh,
    const float* __restrict__ bih, const float* __restrict__ bhh,
    float* __restrict__ yout, float* __restrict__ fin,
    float* __restrict__ xpws) {
  __shared__ float smem[2 * 64 * 68];   // 34.8 KB; rec carves part+hbuf
  const int bid = blockIdx.x;

  if (bid < 32) {
    const int b = bid;
    rec_body(xpws + (size_t)b * Sn * Hn, Whh, bhh, h0 + (size_t)b * Hn,
             yout + (size_t)b * Sn * Hn, fin + (size_t)b * Hn,
             &g_flags[0 * Bn + b], &g_flags[1 * Bn + b],
             smem, smem + 2 * PBUF);
  } else if (bid < 64) {
    const int b = bid - 32;
    rec_body(xpws + (size_t)b * Sn * Hn, Whh + Hn * Hn, bhh + Hn,
             h0 + (size_t)Bn * Hn + (size_t)b * Hn,
             yout + (size_t)b * Sn * Hn, fin + (size_t)Bn * Hn + (size_t)b * Hn,
             &g_flags[2 * Bn + b], nullptr,
             smem, smem + 2 * PBUF);
  } else if (bid < 96) {
    const int b = bid - 64;
    proj_body(x + (size_t)b * Sn * Hn, Wih, bih, xpws + (size_t)b * Sn * Hn,
              nullptr, &g_flags[0 * Bn + b], smem);
  } else {
    const int b = bid - 96;
    proj_body(yout + (size_t)b * Sn * Hn, Wih + Hn * Hn, bih + Hn,
              xpws + (size_t)b * Sn * Hn,
              &g_flags[1 * Bn + b], &g_flags[2 * Bn + b], smem);
  }
}

// ---------------------------------------------------------------------------
// Launch: zero flags, then the single fused pipeline kernel.
// ws needs Bn*Sn*Hn*4 = 64 MiB (xp buffer, shared by both layers in-place).
// ---------------------------------------------------------------------------
extern "C" void kernel_launch(void* const* d_in, const int* in_sizes, int n_in,
                              void* d_out, int out_size, void* d_ws, size_t ws_size,
                              hipStream_t stream) {
  const float* x   = (const float*)d_in[0];
  const float* h0  = (const float*)d_in[1];
  const float* Wih = (const float*)d_in[2];
  const float* Whh = (const float*)d_in[3];
  const float* bih = (const float*)d_in[4];
  const float* bhh = (const float*)d_in[5];

  float* out = (float*)d_out;
  float* yout = out;                              // [Bn,Sn,Hn]
  float* fin  = out + (size_t)Bn * Sn * Hn;       // [Ln,Bn,Hn]
  float* xpws = (float*)d_ws;                     // [Bn,Sn,Hn] scratch

  zero_flags_k<<<1, 128, 0, stream>>>();
  fused<<<128, 512, 0, stream>>>(x, h0, Wih, Whh, bih, bhh, yout, fin, xpws);
}